// Round 1
// baseline (183.871 us; speedup 1.0000x reference)
//
#include <hip/hip_runtime.h>

// XCorrExt: B=32, S=160000, N=320, H=160, TAU=257, LAG_CUT=33
// out[b,f,tau-33] = 2*num/(e0 + e_tau + 1e-5), tau in [33,256]
//
// num[b,f,tau] = sum_n ext[tau+n]*frame[n], frame[n]=xp[160f+n],
// ext[t] = xp[160f+t] (t<320), xp[160f+t-160] (t>=320), wrap f=999: x[b,t-320].
//
// Design: 12 frames/block(192 thr); 16 lanes/frame; each lane: 16 consecutive
// taus (tau0=33+16r) via 32-float rotating register window; LDS swizzled
// phys(i)=i+4*(i>>5) (conflict-free stride-16 reads, 16B-alignment preserved).
// ext stored shifted by 1 so tau0-1 (=0 mod 4) quad loads are float4-aligned.

#define S_LEN   160000
#define FN      1000
#define NWIN    320
#define HOP     160
#define LAG     33
#define OUTT    224
#define NFPB    12
#define BLOCK   192
#define FSTRIDE 1032   // per-frame LDS floats: extS [0,644) + frameArr [644,1032)
#define FA_OFF  644

__device__ __forceinline__ int physi(int i) { return i + ((i >> 5) << 2); }

__global__ __launch_bounds__(BLOCK) void xcorr_kernel(const float* __restrict__ x,
                                                      float* __restrict__ out) {
    __shared__ float lds[NFPB * FSTRIDE + 64];
    const int tid   = threadIdx.x;
    const int b     = blockIdx.y;
    const int fbase = blockIdx.x * NFPB;
    const long bOff = (long)b * S_LEN;

    // ---------------- staging: ext (shifted by 1) + frame arrays ----------------
    for (int g = 0; g < NFPB; ++g) {
        const int f = fbase + g;
        float* E  = &lds[g * FSTRIDE];
        float* Fa = &lds[g * FSTRIDE + FA_OFF];
        // extS[t] = ext[t+1], t = 0..574
        for (int t = tid; t < 575; t += BLOCK) {
            const int tt = t + 1;
            int i = f * HOP + (tt < NWIN ? tt : tt - HOP);
            if (f == FN - 1 && tt >= NWIN) i = tt - NWIN;   // wrap to frame 0
            const float v = (i < S_LEN) ? x[bOff + i] : 0.f;
            E[physi(t)] = v;
        }
        // frameArr[n] = ext[n], n = 0..335 (n>=320 only feeds unused prefetches)
        for (int n = tid; n < 336; n += BLOCK) {
            int i = f * HOP + (n < NWIN ? n : n - HOP);
            if (f == FN - 1 && n >= NWIN) i = n - NWIN;
            const float v = (i < S_LEN) ? x[bOff + i] : 0.f;
            Fa[physi(n)] = v;
        }
    }
    __syncthreads();

    // ---------------- compute ----------------
    const int g  = tid >> 4;
    const int r0 = tid & 15;
    const int r  = (r0 < 14) ? r0 : 13;     // lanes 14,15: duplicate lane 13, masked at store
    const int tau0 = LAG + 16 * r;          // 33 + 16r, == 1 mod 4
    const float* E  = &lds[g * FSTRIDE];
    const float* Fa = &lds[g * FSTRIDE + FA_OFF];

    float acc[16];
    float W[32];        // rotating window: ext[tau0 + m] lives at slot m & 31
    float FQ[4][4];     // rotating frame quads: quad k at slot k & 3
#pragma unroll
    for (int c = 0; c < 16; ++c) acc[c] = 0.f;

#pragma unroll
    for (int j = 0; j < 8; ++j) {           // W <- ext[tau0 .. tau0+31]
        const float4 q = *(const float4*)&E[physi(tau0 - 1 + 4 * j)];
        W[4*j+0] = q.x; W[4*j+1] = q.y; W[4*j+2] = q.z; W[4*j+3] = q.w;
    }
#pragma unroll
    for (int j = 0; j < 4; ++j) {           // FQ <- frame[0..15]
        const float4 q = *(const float4*)&Fa[physi(4 * j)];
        FQ[j][0] = q.x; FQ[j][1] = q.y; FQ[j][2] = q.z; FQ[j][3] = q.w;
    }

    float Tsum = 0.f, e0 = 0.f;

    // 80 rounds of 4 n-steps; unroll 8 so all window indices are static.
    for (int ko = 0; ko < 10; ++ko) {
#pragma unroll
        for (int ki = 0; ki < 8; ++ki) {
            const int k = ko * 8 + ki;
#pragma unroll
            for (int d = 0; d < 4; ++d) {
                const float fv = FQ[ki & 3][d];
#pragma unroll
                for (int c = 0; c < 16; ++c)
                    acc[c] = fmaf(fv, W[(4 * ki + d + c) & 31], acc[c]);
            }
#pragma unroll
            for (int d = 0; d < 4; ++d) {   // Tsum over quad k: ext[tau0+4k .. +3]
                const float v = W[(4 * ki + d) & 31];
                Tsum = fmaf(v, v, Tsum);
            }
#pragma unroll
            for (int d = 0; d < 4; ++d) {   // e0 over frame quad k
                const float v = FQ[ki & 3][d];
                e0 = fmaf(v, v, e0);
            }
            // prefetch W quad k+8 into slots 4ki..4ki+3 (first used at round k+4)
            {
                const float4 q = *(const float4*)&E[physi(tau0 - 1 + 4 * (k + 8))];
                W[(4*ki+0) & 31] = q.x; W[(4*ki+1) & 31] = q.y;
                W[(4*ki+2) & 31] = q.z; W[(4*ki+3) & 31] = q.w;
            }
            // prefetch frame quad k+4 into slot (k+4)&3 == ki&3
            {
                const float4 q = *(const float4*)&Fa[physi(4 * (k + 4))];
                FQ[ki & 3][0] = q.x; FQ[ki & 3][1] = q.y;
                FQ[ki & 3][2] = q.z; FQ[ki & 3][3] = q.w;
            }
        }
    }

    // ---------------- epilogue: e_tau via Tsum - pre - suf ----------------
    float sufv[15], prev[15];
#pragma unroll
    for (int j = 0; j < 15; ++j) {          // ext[tau0+320+j]^2, also completes Tsum
        const float v = E[physi(tau0 + 319 + j)];
        sufv[j] = v * v;
        Tsum += v * v;
    }
#pragma unroll
    for (int j = 0; j < 15; ++j) {          // ext[tau0+j]^2
        const float v = E[physi(tau0 - 1 + j)];
        prev[j] = v * v;
    }

    const int f = fbase + g;
    if (f < FN && r0 < 14) {
        float suf[16];
        suf[15] = 0.f;
#pragma unroll
        for (int c = 14; c >= 0; --c) suf[c] = suf[c + 1] + sufv[c];

        float res[16];
        float pre = 0.f;
#pragma unroll
        for (int c = 0; c < 16; ++c) {
            const float et = Tsum - pre - suf[c];
            res[c] = 2.f * acc[c] / (e0 + et + 1e-5f);
            if (c < 15) pre += prev[c];
        }
        float4* op = (float4*)&out[((long)(b * FN + f)) * OUTT + 16 * r];
        op[0] = make_float4(res[0],  res[1],  res[2],  res[3]);
        op[1] = make_float4(res[4],  res[5],  res[6],  res[7]);
        op[2] = make_float4(res[8],  res[9],  res[10], res[11]);
        op[3] = make_float4(res[12], res[13], res[14], res[15]);
    }
}

extern "C" void kernel_launch(void* const* d_in, const int* in_sizes, int n_in,
                              void* d_out, int out_size, void* d_ws, size_t ws_size,
                              hipStream_t stream) {
    const float* x = (const float*)d_in[0];
    float* out = (float*)d_out;
    dim3 grid((FN + NFPB - 1) / NFPB, 32);   // (84, 32)
    dim3 block(BLOCK);
    hipLaunchKernelGGL(xcorr_kernel, grid, block, 0, stream, x, out);
}

// Round 2
// 146.421 us; speedup vs baseline: 1.2558x; 1.2558x over previous
//
#include <hip/hip_runtime.h>

// XCorrExt: B=32, S=160000, N=320, H=160, TAU=257, LAG_CUT=33
// out[b,f,tau-33] = 2*num/(e0 + e_tau + 1e-5), tau in [33,256]
// num[b,f,tau] = sum_n ext[tau+n]*frame[n]; frame[n] = xp[160f+n]
// ext[t] = xp[160f+t] (t<320) | xp[160f+t-160] (t>=320) | f=999,t>=320: x[t-320]
//
// Layout: 32 frames/block share X = xp[160*fbase .. +5439] (marginal 160
// floats/frame). Fold handled by conditional -160 on LDS index; frame 999's
// wrap via private T[264]. 8 lanes/frame, 28 taus/lane (tau0=33+28r, ==1 mod 4
// so quad loads stay 16B-aligned), 32-float rotating window, zero dead lanes.
// Ext quad starts hit banks {0,28,24,20,16,12,8,4} per group -> perfect
// 32-bank tiling, no swizzle needed.

#define S_LEN 160000
#define FN    1000
#define NF    32
#define BLOCK 256
#define XSZ   (160 * (NF - 1) + 480)   // 5440
#define TOFF  XSZ
#define LDSZ  (XSZ + 264)              // 5704 floats = 22.3 KB

__global__ __launch_bounds__(BLOCK, 4) void xcorr_kernel(const float* __restrict__ x,
                                                         float* __restrict__ out) {
    __shared__ __align__(16) float lds[LDSZ];
    const int tid   = threadIdx.x;
    const int b     = blockIdx.y;
    const int fbase = blockIdx.x * NF;
    const long bOff = (long)b * S_LEN;
    const int gbase = fbase * 160;

    // ---------------- stage shared X (coalesced float4) ----------------
    for (int i = 4 * tid; i < XSZ; i += 4 * BLOCK) {
        const int gx = gbase + i;
        if (gx + 3 < S_LEN) {
            *(float4*)&lds[i] = *(const float4*)&x[bOff + gx];
        } else {
#pragma unroll
            for (int e = 0; e < 4; ++e)
                lds[i + e] = (gx + e < S_LEN) ? x[bOff + gx + e] : 0.f;
        }
    }
    // T[j] = ext_{999}[320+j] = x[b, j]  (only the block containing f=999)
    if (fbase + NF > FN - 1) {
        for (int j = tid; j < 264; j += BLOCK)
            lds[TOFF + j] = x[bOff + j];
    }
    __syncthreads();

    // ---------------- compute ----------------
    const int g    = tid >> 3;           // frame group 0..31
    const int r    = tid & 7;            // lane in group
    const int f    = fbase + g;
    const bool useT = (f == FN - 1);
    const int tau0 = 33 + 28 * r;
    const int wb   = tau0 - 1;           // 32+28r, multiple of 4
    const int xg   = 160 * g;

    float acc[28];
#pragma unroll
    for (int c = 0; c < 28; ++c) acc[c] = 0.f;
    float W[32];       // rotating window: ext[wb + o] at slot o & 31
    float FQ[4][4];    // frame quad k at slot k & 3

#pragma unroll
    for (int j = 0; j < 8; ++j) {        // offsets 0..31 (wb+28 <= 256 < 320: no fold)
        const float4 q = *(const float4*)&lds[xg + wb + 4 * j];
        W[4*j] = q.x; W[4*j+1] = q.y; W[4*j+2] = q.z; W[4*j+3] = q.w;
    }
#pragma unroll
    for (int j = 0; j < 4; ++j) {
        const float4 q = *(const float4*)&lds[xg + 4 * j];
        FQ[j][0] = q.x; FQ[j][1] = q.y; FQ[j][2] = q.z; FQ[j][3] = q.w;
    }

    float Tsum = 0.f, e0 = 0.f;

#pragma unroll 1
    for (int ko = 0; ko < 10; ++ko) {
#pragma unroll
        for (int ki = 0; ki < 8; ++ki) {
            const int k = ko * 8 + ki;
#pragma unroll
            for (int d = 0; d < 4; ++d) {
                const float fv = FQ[ki & 3][d];
#pragma unroll
                for (int c = 0; c < 28; ++c)
                    acc[c] = fmaf(fv, W[(1 + 4 * ki + d + c) & 31], acc[c]);
                const float tv = W[(1 + 4 * ki + d) & 31];   // ext[tau0+4k+d]
                Tsum = fmaf(tv, tv, Tsum);                   // covers offsets 1..320
                e0   = fmaf(fv, fv, e0);                     // frame energy
            }
            // prefetch ext quad k+8 (offsets 4k+32..35 -> slots (4ki..4ki+3)&31)
            {
                const int w = wb + 4 * k + 32;
                int a = xg + w;
                if (w >= 320) a = useT ? (TOFF + (w - 320)) : (a - 160);
                const float4 q = *(const float4*)&lds[a];
                W[(4*ki + 0) & 31] = q.x; W[(4*ki + 1) & 31] = q.y;
                W[(4*ki + 2) & 31] = q.z; W[(4*ki + 3) & 31] = q.w;
            }
            // prefetch frame quad k+4 (slot (k+4)&3 == ki&3, used round k+4)
            {
                const float4 q = *(const float4*)&lds[xg + 4 * k + 16];
                FQ[ki & 3][0] = q.x; FQ[ki & 3][1] = q.y;
                FQ[ki & 3][2] = q.z; FQ[ki & 3][3] = q.w;
            }
        }
    }

    // ---------------- epilogue ----------------
    if (f < FN) {
        float et = Tsum;                 // e_tau[tau0]
        float res[28];
#pragma unroll
        for (int c = 0; c < 28; ++c) {
            const float den = e0 + et + 1e-5f;
            res[c] = 2.f * acc[c] * __builtin_amdgcn_rcpf(den);
            if (c < 27) {
                const float pv = lds[xg + tau0 + c];                       // ext[tau0+c], <320
                const float sv = useT ? lds[TOFF + tau0 + c]               // ext[tau0+320+c]
                                      : lds[xg + tau0 + 160 + c];
                et += sv * sv - pv * pv;
            }
        }
        float* op = &out[((long)(b * FN + f)) * 224 + 28 * r];
#pragma unroll
        for (int q = 0; q < 7; ++q)
            ((float4*)op)[q] = make_float4(res[4*q], res[4*q+1], res[4*q+2], res[4*q+3]);
    }
}

extern "C" void kernel_launch(void* const* d_in, const int* in_sizes, int n_in,
                              void* d_out, int out_size, void* d_ws, size_t ws_size,
                              hipStream_t stream) {
    const float* x = (const float*)d_in[0];
    float* out = (float*)d_out;
    dim3 grid((FN + NF - 1) / NF, 32);   // (32, 32) = 1024 blocks = 4 per CU
    dim3 block(BLOCK);
    hipLaunchKernelGGL(xcorr_kernel, grid, block, 0, stream, x, out);
}